// Round 2
// baseline (2676.679 us; speedup 1.0000x reference)
//
#include <hip/hip_runtime.h>
#include <math.h>

#define GG 32
#define NV (GG * GG * GG)      // 32768 voxels
#define BB 4
#define DD 128
#define ACC_WORDS ((long)BB * NV * DD)   // 16,777,216

// Monotone order-preserving float->uint encoding (for atomicMax on floats).
__device__ __forceinline__ unsigned int enc_f(float f) {
    unsigned int u = __float_as_uint(f);
    return (u & 0x80000000u) ? ~u : (u | 0x80000000u);
}
__device__ __forceinline__ float dec_f(unsigned int u) {
    return __uint_as_float((u & 0x80000000u) ? (u ^ 0x80000000u) : ~u);
}
#define ENC_NEG_INF 0x007FFFFFu
#define ENC_POS_INF 0xFF800000u

// ---- shared-by-both-paths kernels ----

// big: region to fill with ENC_NEG_INF (acc in ws, or out voxel region legacy)
__global__ void k_init(unsigned int* __restrict__ big, long nbig,
                       unsigned int* __restrict__ mm,
                       unsigned int* __restrict__ cnt, long ncnt) {
    long i = blockIdx.x * (long)blockDim.x + threadIdx.x;
    long stride = gridDim.x * (long)blockDim.x;
    for (long j = i; j < nbig; j += stride) big[j] = ENC_NEG_INF;
    for (long j = i; j < ncnt; j += stride) cnt[j] = 0u;
    if (i < BB * 6) {
        int r = (int)(i % 6);
        mm[i] = (r < 3) ? ENC_POS_INF : ENC_NEG_INF;
    }
}

__global__ void k_minmax(const float* __restrict__ xyz,
                         unsigned int* __restrict__ mm, int N) {
    int n = blockIdx.x * blockDim.x + threadIdx.x;
    int b = blockIdx.y;
    float mn[3] = {INFINITY, INFINITY, INFINITY};
    float mx[3] = {-INFINITY, -INFINITY, -INFINITY};
    if (n < N) {
        const float* p = xyz + ((size_t)b * N + n) * 3;
        for (int k = 0; k < 3; k++) { float v = p[k]; mn[k] = v; mx[k] = v; }
    }
    for (int o = 32; o > 0; o >>= 1) {
        for (int k = 0; k < 3; k++) {
            mn[k] = fminf(mn[k], __shfl_xor(mn[k], o));
            mx[k] = fmaxf(mx[k], __shfl_xor(mx[k], o));
        }
    }
    if ((threadIdx.x & 63) == 0) {
        for (int k = 0; k < 3; k++) {
            atomicMin(&mm[b * 6 + k], enc_f(mn[k]));
            atomicMax(&mm[b * 6 + 3 + k], enc_f(mx[k]));
        }
    }
}

__global__ void k_idx(const float* __restrict__ xyz,
                      const unsigned int* __restrict__ mm,
                      float* __restrict__ out_idx,
                      int* __restrict__ cnt, int N) {
    int n = blockIdx.x * blockDim.x + threadIdx.x;
    int b = blockIdx.y;
    if (n >= N) return;
    const float CLIP_HI = 1.0f - 1e-6f;
    const float* p = xyz + ((size_t)b * N + n) * 3;
    int vi[3];
    for (int k = 0; k < 3; k++) {
        float mnv = dec_f(mm[b * 6 + k]);
        float mxv = dec_f(mm[b * 6 + 3 + k]);
        float rng = (mxv - mnv) + 1e-8f;
        float t = (p[k] - mnv) / rng;
        t = fminf(fmaxf(t, 0.0f), CLIP_HI);
        int q = (int)floorf(t * 32.0f);
        q = min(max(q, 0), GG - 1);
        vi[k] = q;
    }
    int idx = vi[0] * (GG * GG) + vi[1] * GG + vi[2];
    out_idx[(size_t)b * N + n] = (float)idx;
    atomicAdd(&cnt[b * NV + idx], 1);
}

__global__ void k_fin_tail(float* __restrict__ out,
                           const unsigned int* __restrict__ mm,
                           long off_cnt, long off_mm) {
    int i = blockIdx.x * blockDim.x + threadIdx.x;
    if (i < BB * NV) {
        int c = ((const int*)out)[off_cnt + i];
        out[off_cnt + i] = (float)c;
    }
    if (i < BB * 3) {
        int b = i / 3, k = i % 3;
        out[off_mm + i]      = dec_f(mm[b * 6 + k]);
        out[off_mm + 12 + i] = dec_f(mm[b * 6 + 3 + k]);
    }
}

// ---- main path: scatter into [B,V,D] accumulator in ws ----

__global__ void k_scatter_t(const float* __restrict__ feat,
                            const float* __restrict__ out_idx,
                            unsigned int* __restrict__ acc, int N) {
    int n = blockIdx.x * blockDim.x + threadIdx.x;
    int b = blockIdx.y;
    if (n >= N) return;
    int idx = (int)out_idx[(size_t)b * N + n];
    const float* fp = feat + (size_t)b * DD * N + n;
    unsigned int* ap = acc + ((size_t)b * NV + idx) * DD;
    #pragma unroll 8
    for (int d = 0; d < DD; d++) {
        atomicMax(ap + d, enc_f(fp[(size_t)d * N]));
    }
}

// [B,V,D] acc -> [B,D,V] out, with empty-voxel -> 0 fixup.
// grid: (V/64, D/32, B); block 256. LDS tile [32][65].
__global__ void k_transpose_fix(const unsigned int* __restrict__ acc,
                                const int* __restrict__ cnt,
                                float* __restrict__ out) {
    __shared__ float tile[32][65];
    __shared__ int zero64[64];
    int v0 = blockIdx.x * 64;
    int d0 = blockIdx.y * 32;
    int b  = blockIdx.z;
    int tid = threadIdx.x;
    if (tid < 64) zero64[tid] = (cnt[(size_t)b * NV + v0 + tid] == 0);
    // load: 32 d (fast) x 8 v per iter
    int dl = tid & 31;
    int vl = tid >> 5;
    const unsigned int* ab = acc + ((size_t)b * NV + v0) * DD + d0;
    for (int r = 0; r < 8; r++) {
        tile[dl][vl + r * 8] = dec_f(ab[(size_t)(vl + r * 8) * DD + dl]);
    }
    __syncthreads();
    // store: 64 v (fast) x 4 d per iter
    int vs = tid & 63;
    int ds = tid >> 6;
    float* ob = out + ((size_t)b * DD + d0) * NV + v0;
    for (int r = 0; r < 8; r++) {
        int d = ds + r * 4;
        float f = zero64[vs] ? 0.0f : tile[d][vs];
        ob[(size_t)d * NV + vs] = f;
    }
}

// ---- legacy fallback (ws too small): atomics directly in out [B,D,V] ----

__global__ void k_scatter_legacy(const float* __restrict__ feat,
                                 const float* __restrict__ out_idx,
                                 unsigned int* __restrict__ vox, int N) {
    int n = blockIdx.x * blockDim.x + threadIdx.x;
    int b = blockIdx.y;
    if (n >= N) return;
    int idx = (int)out_idx[(size_t)b * N + n];
    const float* fp = feat + (size_t)b * DD * N + n;
    unsigned int* vp = vox + (size_t)b * DD * NV + idx;
    #pragma unroll 4
    for (int d = 0; d < DD; d++) {
        atomicMax(vp + (size_t)d * NV, enc_f(fp[(size_t)d * N]));
    }
}

__global__ void k_fin_vox_legacy(unsigned int* __restrict__ out_u,
                                 const int* __restrict__ cnt) {
    size_t i = blockIdx.x * (size_t)blockDim.x + threadIdx.x;
    int b = (int)(i >> 22);
    int v = (int)(i & (NV - 1));
    unsigned int u = out_u[i];
    float f = (cnt[b * NV + v] == 0) ? 0.0f : dec_f(u);
    ((float*)out_u)[i] = f;
}

extern "C" void kernel_launch(void* const* d_in, const int* in_sizes, int n_in,
                              void* d_out, int out_size, void* d_ws, size_t ws_size,
                              hipStream_t stream) {
    const float* features = (const float*)d_in[0];   // [B, D, N]
    const float* xyz      = (const float*)d_in[1];   // [B, N, 3]
    int N = in_sizes[1] / (BB * 3);                  // 100000

    float* out = (float*)d_out;
    unsigned int* out_u = (unsigned int*)d_out;
    unsigned int* ws_u = (unsigned int*)d_ws;

    const long nvox    = ACC_WORDS;                  // out voxel region, 16.7M
    const long off_idx = nvox;
    const long off_cnt = off_idx + (long)BB * N;
    const long ncnt    = (long)BB * NV;
    const long off_mm  = off_cnt + ncnt;

    float* out_idx = out + off_idx;
    int*   cnt     = (int*)(out + off_cnt);

    int nb = (N + 255) / 256;
    bool use_ws = ws_size >= (size_t)ACC_WORDS * 4 + 128;

    if (use_ws) {
        unsigned int* acc = ws_u;                    // [B, V, D]
        unsigned int* mm  = ws_u + ACC_WORDS;        // 24 words
        k_init<<<2048, 256, 0, stream>>>(acc, ACC_WORDS, mm, (unsigned int*)cnt, ncnt);
        k_minmax<<<dim3(nb, BB), 256, 0, stream>>>(xyz, mm, N);
        k_idx<<<dim3(nb, BB), 256, 0, stream>>>(xyz, mm, out_idx, cnt, N);
        k_scatter_t<<<dim3(nb, BB), 256, 0, stream>>>(features, out_idx, acc, N);
        k_transpose_fix<<<dim3(NV / 64, DD / 32, BB), 256, 0, stream>>>(acc, cnt, out);
        k_fin_tail<<<(int)((ncnt + 255) / 256), 256, 0, stream>>>(out, mm, off_cnt, off_mm);
    } else {
        unsigned int* mm = ws_u;
        k_init<<<2048, 256, 0, stream>>>(out_u, nvox, mm, (unsigned int*)cnt, ncnt);
        k_minmax<<<dim3(nb, BB), 256, 0, stream>>>(xyz, mm, N);
        k_idx<<<dim3(nb, BB), 256, 0, stream>>>(xyz, mm, out_idx, cnt, N);
        k_scatter_legacy<<<dim3(nb, BB), 256, 0, stream>>>(features, out_idx, out_u, N);
        k_fin_vox_legacy<<<(unsigned)(nvox / 256), 256, 0, stream>>>(out_u, cnt);
        k_fin_tail<<<(int)((ncnt + 255) / 256), 256, 0, stream>>>(out, mm, off_cnt, off_mm);
    }
}

// Round 3
// 885.454 us; speedup vs baseline: 3.0229x; 3.0229x over previous
//
#include <hip/hip_runtime.h>
#include <math.h>

#define GG 32
#define NV (GG * GG * GG)      // 32768 voxels
#define BB 4
#define DD 128

// Monotone order-preserving float->uint encoding.
__device__ __forceinline__ unsigned int enc_f(float f) {
    unsigned int u = __float_as_uint(f);
    return (u & 0x80000000u) ? ~u : (u | 0x80000000u);
}
__device__ __forceinline__ float dec_f(unsigned int u) {
    return __uint_as_float((u & 0x80000000u) ? (u ^ 0x80000000u) : ~u);
}
#define ENC_NEG_INF 0x007FFFFFu
#define ENC_POS_INF 0xFF800000u

// ws word layout (main path)
#define OFF_FEATT 0L                         // [N,D] per-batch reuse: 12,800,000
#define OFF_IDXI  12800000L                  // [B,N] int idx: 400,000
#define OFF_OFFS  13200000L                  // [B,NV] exclusive offsets: 131,072
#define OFF_CURS  13331072L                  // [B,NV] cursors: 131,072
#define OFF_SORT  13462144L                  // [B,N] sorted point ids: 400,000
#define OFF_MM    13862144L                  // 24 words
#define WS_WORDS  13862168L

__global__ void k_init_small(int* __restrict__ cnt, unsigned int* __restrict__ mm) {
    int i = blockIdx.x * blockDim.x + threadIdx.x;
    if (i < BB * NV) cnt[i] = 0;
    if (i < BB * 6) mm[i] = ((i % 6) < 3) ? ENC_POS_INF : ENC_NEG_INF;
}

__global__ void k_minmax(const float* __restrict__ xyz,
                         unsigned int* __restrict__ mm, int N) {
    int n = blockIdx.x * blockDim.x + threadIdx.x;
    int b = blockIdx.y;
    float mn[3] = {INFINITY, INFINITY, INFINITY};
    float mx[3] = {-INFINITY, -INFINITY, -INFINITY};
    if (n < N) {
        const float* p = xyz + ((size_t)b * N + n) * 3;
        for (int k = 0; k < 3; k++) { float v = p[k]; mn[k] = v; mx[k] = v; }
    }
    for (int o = 32; o > 0; o >>= 1) {
        for (int k = 0; k < 3; k++) {
            mn[k] = fminf(mn[k], __shfl_xor(mn[k], o));
            mx[k] = fmaxf(mx[k], __shfl_xor(mx[k], o));
        }
    }
    if ((threadIdx.x & 63) == 0) {
        for (int k = 0; k < 3; k++) {
            atomicMin(&mm[b * 6 + k], enc_f(mn[k]));
            atomicMax(&mm[b * 6 + 3 + k], enc_f(mx[k]));
        }
    }
}

__global__ void k_idx(const float* __restrict__ xyz,
                      const unsigned int* __restrict__ mm,
                      float* __restrict__ out_idx,
                      int* __restrict__ idx_i,
                      int* __restrict__ cnt, int N) {
    int n = blockIdx.x * blockDim.x + threadIdx.x;
    int b = blockIdx.y;
    if (n >= N) return;
    const float CLIP_HI = 1.0f - 1e-6f;
    const float* p = xyz + ((size_t)b * N + n) * 3;
    int vi[3];
    for (int k = 0; k < 3; k++) {
        float mnv = dec_f(mm[b * 6 + k]);
        float mxv = dec_f(mm[b * 6 + 3 + k]);
        float rng = (mxv - mnv) + 1e-8f;
        float t = (p[k] - mnv) / rng;
        t = fminf(fmaxf(t, 0.0f), CLIP_HI);
        int q = (int)floorf(t * 32.0f);
        q = min(max(q, 0), GG - 1);
        vi[k] = q;
    }
    int idx = vi[0] * (GG * GG) + vi[1] * GG + vi[2];
    out_idx[(size_t)b * N + n] = (float)idx;
    idx_i[(size_t)b * N + n] = idx;
    atomicAdd(&cnt[b * NV + idx], 1);
}

// One block of 1024 threads per batch; exclusive scan of cnt[b][0..NV).
__global__ void k_scan(const int* __restrict__ cnt,
                       int* __restrict__ offs, int* __restrict__ curs) {
    __shared__ int part[1024];
    int b = blockIdx.x, t = threadIdx.x;
    const int PER = NV / 1024;          // 32
    int base = b * NV + t * PER;
    int loc[PER];
    int s = 0;
    #pragma unroll
    for (int i = 0; i < PER; i++) { loc[i] = cnt[base + i]; s += loc[i]; }
    part[t] = s;
    __syncthreads();
    for (int o = 1; o < 1024; o <<= 1) {
        int v = (t >= o) ? part[t - o] : 0;
        __syncthreads();
        part[t] += v;
        __syncthreads();
    }
    int ex = part[t] - s;               // exclusive prefix of this chunk
    #pragma unroll
    for (int i = 0; i < PER; i++) {
        offs[base + i] = ex;
        curs[base + i] = ex;
        ex += loc[i];
    }
}

__global__ void k_sortscatter(const int* __restrict__ idx_i,
                              int* __restrict__ curs,
                              int* __restrict__ sorted, int N) {
    int n = blockIdx.x * blockDim.x + threadIdx.x;
    int b = blockIdx.y;
    if (n >= N) return;
    int idx = idx_i[(size_t)b * N + n];
    int pos = atomicAdd(&curs[b * NV + idx], 1);
    sorted[(size_t)b * N + pos] = n;
}

// [D,N] -> [N,D] tiled transpose for one batch.
__global__ void k_transpose(const float* __restrict__ feat,
                            float* __restrict__ featT, int N, int b) {
    __shared__ float tile[32][33];
    int n0 = blockIdx.x * 32;
    int d0 = blockIdx.y * 32;
    int tid = threadIdx.x;
    int tx = tid & 31, ty = tid >> 5;   // ty in 0..7
    const float* fb = feat + (size_t)b * DD * N;
    #pragma unroll
    for (int r = 0; r < 4; r++) {
        int dl = ty + r * 8;
        int nn = n0 + tx;
        if (nn < N) tile[dl][tx] = fb[(size_t)(d0 + dl) * N + nn];
    }
    __syncthreads();
    #pragma unroll
    for (int r = 0; r < 4; r++) {
        int nl = ty + r * 8;
        int nn = n0 + nl;
        if (nn < N) featT[(size_t)nn * DD + d0 + tx] = tile[tx][nl];
    }
}

// One block (128 threads) per voxel: max over its sorted point list,
// write directly to out[b][d][v]; empty voxel -> 0.
__global__ void k_reduce(const float* __restrict__ featT,
                         const int* __restrict__ sorted,
                         const int* __restrict__ offs,
                         float* __restrict__ out, int N, int b) {
    int v = blockIdx.x;
    int d = threadIdx.x;
    int off = offs[b * NV + v];
    int end = (v == NV - 1) ? N : offs[b * NV + v + 1];
    float m = -INFINITY;
    for (int i = off; i < end; i++) {
        int p = sorted[(size_t)b * N + i];
        m = fmaxf(m, featT[(size_t)p * DD + d]);
    }
    out[((size_t)b * DD + d) * NV + v] = (end > off) ? m : 0.0f;
}

__global__ void k_fin_tail(float* __restrict__ out,
                           const unsigned int* __restrict__ mm,
                           long off_cnt, long off_mm) {
    int i = blockIdx.x * blockDim.x + threadIdx.x;
    if (i < BB * NV) {
        int c = ((const int*)out)[off_cnt + i];
        out[off_cnt + i] = (float)c;
    }
    if (i < BB * 3) {
        int b = i / 3, k = i % 3;
        out[off_mm + i]      = dec_f(mm[b * 6 + k]);
        out[off_mm + 12 + i] = dec_f(mm[b * 6 + 3 + k]);
    }
}

// ---- legacy fallback (tiny ws): atomics directly into out [B,D,V] ----

__global__ void k_init_legacy(unsigned int* __restrict__ out_u, long nvox,
                              unsigned int* __restrict__ mm,
                              unsigned int* __restrict__ cnt, long ncnt) {
    long i = blockIdx.x * (long)blockDim.x + threadIdx.x;
    long stride = gridDim.x * (long)blockDim.x;
    for (long j = i; j < nvox; j += stride) out_u[j] = ENC_NEG_INF;
    for (long j = i; j < ncnt; j += stride) cnt[j] = 0u;
    if (i < BB * 6) mm[i] = ((i % 6) < 3) ? ENC_POS_INF : ENC_NEG_INF;
}

__global__ void k_scatter_legacy(const float* __restrict__ feat,
                                 const float* __restrict__ out_idx,
                                 unsigned int* __restrict__ vox, int N) {
    int n = blockIdx.x * blockDim.x + threadIdx.x;
    int b = blockIdx.y;
    if (n >= N) return;
    int idx = (int)out_idx[(size_t)b * N + n];
    const float* fp = feat + (size_t)b * DD * N + n;
    unsigned int* vp = vox + (size_t)b * DD * NV + idx;
    #pragma unroll 4
    for (int d = 0; d < DD; d++) {
        atomicMax(vp + (size_t)d * NV, enc_f(fp[(size_t)d * N]));
    }
}

__global__ void k_fin_vox_legacy(unsigned int* __restrict__ out_u,
                                 const int* __restrict__ cnt) {
    size_t i = blockIdx.x * (size_t)blockDim.x + threadIdx.x;
    int b = (int)(i >> 22);
    int v = (int)(i & (NV - 1));
    unsigned int u = out_u[i];
    float f = (cnt[b * NV + v] == 0) ? 0.0f : dec_f(u);
    ((float*)out_u)[i] = f;
}

extern "C" void kernel_launch(void* const* d_in, const int* in_sizes, int n_in,
                              void* d_out, int out_size, void* d_ws, size_t ws_size,
                              hipStream_t stream) {
    const float* features = (const float*)d_in[0];   // [B, D, N]
    const float* xyz      = (const float*)d_in[1];   // [B, N, 3]
    int N = in_sizes[1] / (BB * 3);                  // 100000

    float* out = (float*)d_out;
    unsigned int* ws_u = (unsigned int*)d_ws;

    const long nvox    = (long)BB * DD * NV;
    const long off_idx = nvox;
    const long off_cnt = off_idx + (long)BB * N;
    const long ncnt    = (long)BB * NV;
    const long off_mm  = off_cnt + ncnt;

    float* out_idx = out + off_idx;
    int*   cnt     = (int*)(out + off_cnt);

    int nb = (N + 255) / 256;

    if (ws_size >= (size_t)WS_WORDS * 4) {
        float* featT  = (float*)ws_u + OFF_FEATT;
        int*   idx_i  = (int*)ws_u + OFF_IDXI;
        int*   offs   = (int*)ws_u + OFF_OFFS;
        int*   curs   = (int*)ws_u + OFF_CURS;
        int*   sorted = (int*)ws_u + OFF_SORT;
        unsigned int* mm = ws_u + OFF_MM;

        k_init_small<<<(BB * NV + 255) / 256, 256, 0, stream>>>(cnt, mm);
        k_minmax<<<dim3(nb, BB), 256, 0, stream>>>(xyz, mm, N);
        k_idx<<<dim3(nb, BB), 256, 0, stream>>>(xyz, mm, out_idx, idx_i, cnt, N);
        k_scan<<<BB, 1024, 0, stream>>>(cnt, offs, curs);
        k_sortscatter<<<dim3(nb, BB), 256, 0, stream>>>(idx_i, curs, sorted, N);
        for (int b = 0; b < BB; b++) {
            k_transpose<<<dim3((N + 31) / 32, DD / 32), 256, 0, stream>>>(
                features, featT, N, b);
            k_reduce<<<NV, DD, 0, stream>>>(featT, sorted, offs, out, N, b);
        }
        k_fin_tail<<<(int)((ncnt + 255) / 256), 256, 0, stream>>>(out, mm, off_cnt, off_mm);
    } else {
        unsigned int* mm = ws_u;
        k_init_legacy<<<2048, 256, 0, stream>>>((unsigned int*)out, nvox, mm,
                                                (unsigned int*)cnt, ncnt);
        k_minmax<<<dim3(nb, BB), 256, 0, stream>>>(xyz, mm, N);
        k_idx<<<dim3(nb, BB), 256, 0, stream>>>(xyz, mm, out_idx,
                                                (int*)(out + off_idx), cnt, N);
        // note: legacy k_idx writes idx_i into out_idx region (int aliasing is
        // unused there) — reuse float path only:
        k_scatter_legacy<<<dim3(nb, BB), 256, 0, stream>>>(features, out_idx,
                                                           (unsigned int*)out, N);
        k_fin_vox_legacy<<<(unsigned)(nvox / 256), 256, 0, stream>>>(
            (unsigned int*)out, cnt);
        k_fin_tail<<<(int)((ncnt + 255) / 256), 256, 0, stream>>>(out, mm, off_cnt, off_mm);
    }
}

// Round 4
// 629.509 us; speedup vs baseline: 4.2520x; 1.4066x over previous
//
#include <hip/hip_runtime.h>
#include <math.h>

#define GG 32
#define NV (GG * GG * GG)      // 32768 voxels
#define BB 4
#define DD 128

// Monotone order-preserving float->uint encoding.
__device__ __forceinline__ unsigned int enc_f(float f) {
    unsigned int u = __float_as_uint(f);
    return (u & 0x80000000u) ? ~u : (u | 0x80000000u);
}
__device__ __forceinline__ float dec_f(unsigned int u) {
    return __uint_as_float((u & 0x80000000u) ? (u ^ 0x80000000u) : ~u);
}
#define ENC_NEG_INF 0x007FFFFFu
#define ENC_POS_INF 0xFF800000u

__global__ void k_init_small(int* __restrict__ cnt, unsigned int* __restrict__ mm) {
    int i = blockIdx.x * blockDim.x + threadIdx.x;
    if (i < BB * NV) cnt[i] = 0;
    if (i < BB * 6) mm[i] = ((i % 6) < 3) ? ENC_POS_INF : ENC_NEG_INF;
}

// grid (64, BB), block 256. Per-thread grid-stride accumulate, wave butterfly,
// LDS cross-wave, ONE thread per block does the 6 atomics (contention fix).
__global__ void k_minmax(const float* __restrict__ xyz,
                         unsigned int* __restrict__ mm, int N) {
    int b = blockIdx.y;
    int tid = threadIdx.x;
    int gid = blockIdx.x * blockDim.x + tid;
    int stride = gridDim.x * blockDim.x;
    float mn[3] = {INFINITY, INFINITY, INFINITY};
    float mx[3] = {-INFINITY, -INFINITY, -INFINITY};
    const float* base = xyz + (size_t)b * N * 3;
    for (int n = gid; n < N; n += stride) {
        const float* p = base + (size_t)n * 3;
        #pragma unroll
        for (int k = 0; k < 3; k++) {
            float v = p[k];
            mn[k] = fminf(mn[k], v);
            mx[k] = fmaxf(mx[k], v);
        }
    }
    for (int o = 32; o > 0; o >>= 1) {
        #pragma unroll
        for (int k = 0; k < 3; k++) {
            mn[k] = fminf(mn[k], __shfl_xor(mn[k], o));
            mx[k] = fmaxf(mx[k], __shfl_xor(mx[k], o));
        }
    }
    __shared__ float smn[4][3], smx[4][3];
    int w = tid >> 6;
    if ((tid & 63) == 0) {
        #pragma unroll
        for (int k = 0; k < 3; k++) { smn[w][k] = mn[k]; smx[w][k] = mx[k]; }
    }
    __syncthreads();
    if (tid == 0) {
        #pragma unroll
        for (int k = 0; k < 3; k++) {
            float a = fminf(fminf(smn[0][k], smn[1][k]), fminf(smn[2][k], smn[3][k]));
            float c = fmaxf(fmaxf(smx[0][k], smx[1][k]), fmaxf(smx[2][k], smx[3][k]));
            atomicMin(&mm[b * 6 + k], enc_f(a));
            atomicMax(&mm[b * 6 + 3 + k], enc_f(c));
        }
    }
}

__global__ void k_idx(const float* __restrict__ xyz,
                      const unsigned int* __restrict__ mm,
                      float* __restrict__ out_idx,
                      int* __restrict__ idx_i,
                      int* __restrict__ cnt, int N) {
    int n = blockIdx.x * blockDim.x + threadIdx.x;
    int b = blockIdx.y;
    if (n >= N) return;
    const float CLIP_HI = 1.0f - 1e-6f;
    const float* p = xyz + ((size_t)b * N + n) * 3;
    int vi[3];
    #pragma unroll
    for (int k = 0; k < 3; k++) {
        float mnv = dec_f(mm[b * 6 + k]);
        float mxv = dec_f(mm[b * 6 + 3 + k]);
        float rng = (mxv - mnv) + 1e-8f;
        float t = (p[k] - mnv) / rng;
        t = fminf(fmaxf(t, 0.0f), CLIP_HI);
        int q = (int)floorf(t * 32.0f);
        q = min(max(q, 0), GG - 1);
        vi[k] = q;
    }
    int idx = vi[0] * (GG * GG) + vi[1] * GG + vi[2];
    out_idx[(size_t)b * N + n] = (float)idx;
    idx_i[(size_t)b * N + n] = idx;
    atomicAdd(&cnt[b * NV + idx], 1);
}

// One block of 1024 threads per batch; exclusive scan of cnt[b][0..NV).
__global__ void k_scan(const int* __restrict__ cnt,
                       int* __restrict__ offs, int* __restrict__ curs) {
    __shared__ int part[1024];
    int b = blockIdx.x, t = threadIdx.x;
    const int PER = NV / 1024;          // 32
    int base = b * NV + t * PER;
    int loc[PER];
    int s = 0;
    #pragma unroll
    for (int i = 0; i < PER; i++) { loc[i] = cnt[base + i]; s += loc[i]; }
    part[t] = s;
    __syncthreads();
    for (int o = 1; o < 1024; o <<= 1) {
        int v = (t >= o) ? part[t - o] : 0;
        __syncthreads();
        part[t] += v;
        __syncthreads();
    }
    int ex = part[t] - s;
    #pragma unroll
    for (int i = 0; i < PER; i++) {
        offs[base + i] = ex;
        curs[base + i] = ex;
        ex += loc[i];
    }
}

__global__ void k_sortscatter(const int* __restrict__ idx_i,
                              int* __restrict__ curs,
                              int* __restrict__ sorted, int N) {
    int n = blockIdx.x * blockDim.x + threadIdx.x;
    int b = blockIdx.y;
    if (n >= N) return;
    int idx = idx_i[(size_t)b * N + n];
    int pos = atomicAdd(&curs[b * NV + idx], 1);
    sorted[(size_t)b * N + pos] = n;
}

// [D,N] -> [N,D] tiled transpose. b = b_base + blockIdx.z; featT offset by
// blockIdx.z * fstride (fstride = N*DD in batched path, unused when gridZ==1).
__global__ void k_transpose(const float* __restrict__ feat,
                            float* __restrict__ featT, int N,
                            int b_base, size_t fstride) {
    __shared__ float tile[32][33];
    int b = b_base + blockIdx.z;
    float* ft = featT + (size_t)blockIdx.z * fstride;
    int n0 = blockIdx.x * 32;
    int d0 = blockIdx.y * 32;
    int tid = threadIdx.x;
    int tx = tid & 31, ty = tid >> 5;   // ty in 0..7
    const float* fb = feat + (size_t)b * DD * N;
    #pragma unroll
    for (int r = 0; r < 4; r++) {
        int dl = ty + r * 8;
        int nn = n0 + tx;
        if (nn < N) tile[dl][tx] = fb[(size_t)(d0 + dl) * N + nn];
    }
    __syncthreads();
    #pragma unroll
    for (int r = 0; r < 4; r++) {
        int nl = ty + r * 8;
        int nn = n0 + nl;
        if (nn < N) ft[(size_t)nn * DD + d0 + tx] = tile[tx][nl];
    }
}

// One block (128 threads) per voxel: max over its sorted point list,
// write directly to out[b][d][v]; empty voxel -> 0.
__global__ void k_reduce(const float* __restrict__ featT,
                         const int* __restrict__ sorted,
                         const int* __restrict__ offs,
                         float* __restrict__ out, int N,
                         int b_base, size_t fstride) {
    int b = b_base + blockIdx.z;
    const float* ft = featT + (size_t)blockIdx.z * fstride;
    int v = blockIdx.x;
    int d = threadIdx.x;
    int off = offs[b * NV + v];
    int end = (v == NV - 1) ? N : offs[b * NV + v + 1];
    float m = -INFINITY;
    for (int i = off; i < end; i++) {
        int p = sorted[(size_t)b * N + i];
        m = fmaxf(m, ft[(size_t)p * DD + d]);
    }
    out[((size_t)b * DD + d) * NV + v] = (end > off) ? m : 0.0f;
}

__global__ void k_fin_tail(float* __restrict__ out,
                           const unsigned int* __restrict__ mm,
                           long off_cnt, long off_mm) {
    int i = blockIdx.x * blockDim.x + threadIdx.x;
    if (i < BB * NV) {
        int c = ((const int*)out)[off_cnt + i];
        out[off_cnt + i] = (float)c;
    }
    if (i < BB * 3) {
        int b = i / 3, k = i % 3;
        out[off_mm + i]      = dec_f(mm[b * 6 + k]);
        out[off_mm + 12 + i] = dec_f(mm[b * 6 + 3 + k]);
    }
}

// ---- legacy fallback (tiny ws): atomics directly into out [B,D,V] ----

__global__ void k_init_legacy(unsigned int* __restrict__ out_u, long nvox,
                              unsigned int* __restrict__ mm,
                              unsigned int* __restrict__ cnt, long ncnt) {
    long i = blockIdx.x * (long)blockDim.x + threadIdx.x;
    long stride = gridDim.x * (long)blockDim.x;
    for (long j = i; j < nvox; j += stride) out_u[j] = ENC_NEG_INF;
    for (long j = i; j < ncnt; j += stride) cnt[j] = 0u;
    if (i < BB * 6) mm[i] = ((i % 6) < 3) ? ENC_POS_INF : ENC_NEG_INF;
}

__global__ void k_scatter_legacy(const float* __restrict__ feat,
                                 const float* __restrict__ out_idx,
                                 unsigned int* __restrict__ vox, int N) {
    int n = blockIdx.x * blockDim.x + threadIdx.x;
    int b = blockIdx.y;
    if (n >= N) return;
    int idx = (int)out_idx[(size_t)b * N + n];
    const float* fp = feat + (size_t)b * DD * N + n;
    unsigned int* vp = vox + (size_t)b * DD * NV + idx;
    #pragma unroll 4
    for (int d = 0; d < DD; d++) {
        atomicMax(vp + (size_t)d * NV, enc_f(fp[(size_t)d * N]));
    }
}

__global__ void k_fin_vox_legacy(unsigned int* __restrict__ out_u,
                                 const int* __restrict__ cnt) {
    size_t i = blockIdx.x * (size_t)blockDim.x + threadIdx.x;
    int b = (int)(i >> 22);
    int v = (int)(i & (NV - 1));
    unsigned int u = out_u[i];
    float f = (cnt[b * NV + v] == 0) ? 0.0f : dec_f(u);
    ((float*)out_u)[i] = f;
}

extern "C" void kernel_launch(void* const* d_in, const int* in_sizes, int n_in,
                              void* d_out, int out_size, void* d_ws, size_t ws_size,
                              hipStream_t stream) {
    const float* features = (const float*)d_in[0];   // [B, D, N]
    const float* xyz      = (const float*)d_in[1];   // [B, N, 3]
    int N = in_sizes[1] / (BB * 3);                  // 100000

    float* out = (float*)d_out;
    unsigned int* ws_u = (unsigned int*)d_ws;

    const long nvox    = (long)BB * DD * NV;
    const long off_idx = nvox;
    const long off_cnt = off_idx + (long)BB * N;
    const long ncnt    = (long)BB * NV;
    const long off_mm  = off_cnt + ncnt;

    float* out_idx = out + off_idx;
    int*   cnt     = (int*)(out + off_cnt);

    int nb = (N + 255) / 256;

    // ws extras (after featT region): idx_i [B*N], offs [B*NV], curs [B*NV],
    // sorted [B*N], mm [24]
    const long extras = (long)BB * N * 2 + (long)BB * NV * 2 + 24;
    const long featT_small = (long)N * DD;           // one batch
    const long featT_big   = (long)BB * N * DD;      // all batches

    bool big   = ws_size >= (size_t)(featT_big + extras) * 4;
    bool small = ws_size >= (size_t)(featT_small + extras) * 4;

    if (small || big) {
        long ftw = big ? featT_big : featT_small;
        float* featT  = (float*)ws_u;
        int*   idx_i  = (int*)ws_u + ftw;
        int*   offs   = idx_i + (long)BB * N;
        int*   curs   = offs + (long)BB * NV;
        int*   sorted = curs + (long)BB * NV;
        unsigned int* mm = (unsigned int*)(sorted + (long)BB * N);

        k_init_small<<<(BB * NV + 255) / 256, 256, 0, stream>>>(cnt, mm);
        k_minmax<<<dim3(64, BB), 256, 0, stream>>>(xyz, mm, N);
        k_idx<<<dim3(nb, BB), 256, 0, stream>>>(xyz, mm, out_idx, idx_i, cnt, N);
        k_scan<<<BB, 1024, 0, stream>>>(cnt, offs, curs);
        k_sortscatter<<<dim3(nb, BB), 256, 0, stream>>>(idx_i, curs, sorted, N);
        if (big) {
            size_t fstride = (size_t)N * DD;
            k_transpose<<<dim3((N + 31) / 32, DD / 32, BB), 256, 0, stream>>>(
                features, featT, N, 0, fstride);
            k_reduce<<<dim3(NV, 1, BB), DD, 0, stream>>>(
                featT, sorted, offs, out, N, 0, fstride);
        } else {
            for (int b = 0; b < BB; b++) {
                k_transpose<<<dim3((N + 31) / 32, DD / 32, 1), 256, 0, stream>>>(
                    features, featT, N, b, 0);
                k_reduce<<<dim3(NV, 1, 1), DD, 0, stream>>>(
                    featT, sorted, offs, out, N, b, 0);
            }
        }
        k_fin_tail<<<(int)((ncnt + 255) / 256), 256, 0, stream>>>(out, mm, off_cnt, off_mm);
    } else {
        unsigned int* mm = ws_u;
        k_init_legacy<<<2048, 256, 0, stream>>>((unsigned int*)out, nvox, mm,
                                                (unsigned int*)cnt, ncnt);
        k_minmax<<<dim3(64, BB), 256, 0, stream>>>(xyz, mm, N);
        k_idx<<<dim3(nb, BB), 256, 0, stream>>>(xyz, mm, out_idx,
                                                (int*)(out + off_idx), cnt, N);
        k_scatter_legacy<<<dim3(nb, BB), 256, 0, stream>>>(features, out_idx,
                                                           (unsigned int*)out, N);
        k_fin_vox_legacy<<<(unsigned)(nvox / 256), 256, 0, stream>>>(
            (unsigned int*)out, cnt);
        k_fin_tail<<<(int)((ncnt + 255) / 256), 256, 0, stream>>>(out, mm, off_cnt, off_mm);
    }
}